// Round 1
// baseline (1180.543 us; speedup 1.0000x reference)
//
#include <hip/hip_runtime.h>
#include <cstddef>
#include <cstdint>

#define NNODES 8192
#define BATCH  16
#define FDIM   66      // IN_DIM + HID
#define HID    64
#define CCH    1056    // FDIM * BATCH channels per node
#define NEDGE  131072
#define NFB    8650752 // NNODES * CCH
#define SN     524288  // NNODES * HID  (per-batch state stride)
#define OUTHALF 8388608 // BATCH * SN

// ---------------- CSR construction ----------------

__global__ void zero_counts_kernel(int* __restrict__ c1, int* __restrict__ c2) {
    int i = blockIdx.x * 256 + threadIdx.x;
    if (i < NNODES) { c1[i] = 0; c2[i] = 0; }
}

__global__ void hist_kernel(const int* __restrict__ src, const int* __restrict__ dst,
                            int* __restrict__ c1, int* __restrict__ c2) {
    int e = blockIdx.x * 256 + threadIdx.x;
    if (e < NEDGE) {
        atomicAdd(&c1[src[e]], 1);
        atomicAdd(&c2[dst[e]], 1);
    }
}

// single block, 1024 threads, scans 8192 counts -> rowptr (exclusive+1) and cursor (exclusive)
__global__ __launch_bounds__(1024) void scan_kernel(const int* __restrict__ counts,
                                                    int* __restrict__ rowptr,
                                                    int* __restrict__ cursor) {
    __shared__ int sh[1024];
    int tid = threadIdx.x;
    int base = tid * 8;
    int local[8];
    int sum = 0;
#pragma unroll
    for (int j = 0; j < 8; ++j) { local[j] = counts[base + j]; sum += local[j]; }
    sh[tid] = sum;
    __syncthreads();
    for (int off = 1; off < 1024; off <<= 1) {
        int v = (tid >= off) ? sh[tid - off] : 0;
        __syncthreads();
        sh[tid] += v;
        __syncthreads();
    }
    int p = sh[tid] - sum; // exclusive prefix of this thread's chunk
#pragma unroll
    for (int j = 0; j < 8; ++j) {
        cursor[base + j] = p;
        p += local[j];
        rowptr[base + j + 1] = p;
    }
    if (tid == 0) rowptr[0] = 0;
}

__global__ void scatter_kernel(const int* __restrict__ src, const int* __restrict__ dst,
                               const float* __restrict__ v1, const float* __restrict__ v2,
                               int* __restrict__ cur1, int* __restrict__ cur2,
                               int* __restrict__ cols1, float* __restrict__ valsC1,
                               int* __restrict__ cols2, float* __restrict__ valsC2) {
    int e = blockIdx.x * 256 + threadIdx.x;
    if (e < NEDGE) {
        int r1 = src[e];
        int p1 = atomicAdd(&cur1[r1], 1);
        cols1[p1] = dst[e];
        valsC1[p1] = v1[e];
        int r2 = dst[e];
        int p2 = atomicAdd(&cur2[r2], 1);
        cols2[p2] = src[e];
        valsC2[p2] = v2[e];
    }
}

// ---------------- build x0: X[0][n][f][b] ----------------

__global__ void build_x0_kernel(const float* __restrict__ inputs, const float* __restrict__ state,
                                float* __restrict__ X0) {
    int idx = blockIdx.x * 256 + threadIdx.x;
    if (idx >= NFB) return;
    int b = idx & 15;
    int t = idx >> 4;
    int f = t % FDIM;
    int n = t / FDIM;
    float v;
    if (f < 2) v = inputs[(size_t)b * (NNODES * 2) + n * 2 + f];
    else       v = state[(size_t)b * SN + n * HID + (f - 2)];
    X0[idx] = v;
}

// ---------------- SPMM: y[n] = alpha * sum_e vals[e]*x[cols[e]] + beta * xp[n] ----------------

__global__ __launch_bounds__(256) void spmm_kernel(const int* __restrict__ rowptr,
                                                   const int* __restrict__ cols,
                                                   const float* __restrict__ vals,
                                                   const float* __restrict__ x,
                                                   const float* __restrict__ xp,
                                                   float* __restrict__ y,
                                                   float alpha, float beta) {
    int n = blockIdx.x;
    int tid = threadIdx.x;
    int s = rowptr[n], e = rowptr[n + 1];
    float4 a0 = make_float4(0.f, 0.f, 0.f, 0.f);
    float4 a1 = make_float4(0.f, 0.f, 0.f, 0.f);
    bool tail = tid < 8; // 1056/4 = 264 float4s; threads 0..7 cover 256..263
    for (int i = s; i < e; ++i) {
        float v = vals[i];
        int c = cols[i];
        const float4* xb = (const float4*)(x + (size_t)c * CCH);
        float4 t0 = xb[tid];
        a0.x += v * t0.x; a0.y += v * t0.y; a0.z += v * t0.z; a0.w += v * t0.w;
        if (tail) {
            float4 t1 = xb[256 + tid];
            a1.x += v * t1.x; a1.y += v * t1.y; a1.z += v * t1.z; a1.w += v * t1.w;
        }
    }
    float4* yb = (float4*)(y + (size_t)n * CCH);
    if (beta != 0.f) {
        const float4* xpb = (const float4*)(xp + (size_t)n * CCH);
        float4 p = xpb[tid];
        yb[tid] = make_float4(alpha * a0.x + beta * p.x, alpha * a0.y + beta * p.y,
                              alpha * a0.z + beta * p.z, alpha * a0.w + beta * p.w);
        if (tail) {
            float4 p1 = xpb[256 + tid];
            yb[256 + tid] = make_float4(alpha * a1.x + beta * p1.x, alpha * a1.y + beta * p1.y,
                                        alpha * a1.z + beta * p1.z, alpha * a1.w + beta * p1.w);
        }
    } else {
        yb[tid] = make_float4(alpha * a0.x, alpha * a0.y, alpha * a0.z, alpha * a0.w);
        if (tail) yb[256 + tid] = make_float4(alpha * a1.x, alpha * a1.y, alpha * a1.z, alpha * a1.w);
    }
}

// ---------------- gate GEMM + sigmoid + r*state writeback + u store ----------------
// block = 256 threads = (col 0..127) x (half 0..1); each thread: 8 batch rows, 1 col.

__global__ __launch_bounds__(256) void gate_kernel(const float* __restrict__ X,
                                                   const float* __restrict__ Wg,
                                                   const float* __restrict__ bg,
                                                   const float* __restrict__ state,
                                                   float* __restrict__ U,
                                                   float* __restrict__ X0mut) {
    __shared__ __align__(16) float xt[5 * CCH];
    int n = blockIdx.x;
    int tid = threadIdx.x;
    for (int i = tid; i < 5 * CCH; i += 256) {
        int m = i / CCH;
        int r = i - m * CCH;
        xt[i] = X[(size_t)m * NFB + (size_t)n * CCH + r];
    }
    __syncthreads();
    int col = tid & 127;
    int half = tid >> 7;
    float acc[8];
    float bias = bg[col];
#pragma unroll
    for (int i = 0; i < 8; ++i) acc[i] = bias;
    for (int f = 0; f < FDIM; ++f) {
#pragma unroll
        for (int m = 0; m < 5; ++m) {
            float w = Wg[(f * 5 + m) * 128 + col];
            const float* xp = &xt[m * CCH + f * 16 + half * 8];
            float4 xa = *(const float4*)xp;
            float4 xb = *(const float4*)(xp + 4);
            acc[0] += xa.x * w; acc[1] += xa.y * w; acc[2] += xa.z * w; acc[3] += xa.w * w;
            acc[4] += xb.x * w; acc[5] += xb.y * w; acc[6] += xb.z * w; acc[7] += xb.w * w;
        }
    }
#pragma unroll
    for (int i = 0; i < 8; ++i) {
        int b = half * 8 + i;
        float v = 1.f / (1.f + __expf(-acc[i]));
        if (col < HID) {
            float s = state[(size_t)b * SN + n * HID + col];
            X0mut[((size_t)n * FDIM + 2 + col) * 16 + b] = v * s; // xc state part
        } else {
            U[(size_t)b * SN + n * HID + (col - HID)] = v;
        }
    }
}

// ---------------- candidate GEMM + tanh + GRU update + output ----------------
// block = 256 threads = (col 0..63) x (quarter 0..3); each thread: 4 batch rows, 1 col.

__global__ __launch_bounds__(256) void cand_kernel(const float* __restrict__ X,
                                                   const float* __restrict__ Wc,
                                                   const float* __restrict__ bc,
                                                   const float* __restrict__ state,
                                                   const float* __restrict__ U,
                                                   float* __restrict__ out) {
    __shared__ __align__(16) float xt[5 * CCH];
    int n = blockIdx.x;
    int tid = threadIdx.x;
    for (int i = tid; i < 5 * CCH; i += 256) {
        int m = i / CCH;
        int r = i - m * CCH;
        xt[i] = X[(size_t)m * NFB + (size_t)n * CCH + r];
    }
    __syncthreads();
    int col = tid & 63;
    int q = tid >> 6;
    float acc[4];
    float bias = bc[col];
#pragma unroll
    for (int i = 0; i < 4; ++i) acc[i] = bias;
    for (int f = 0; f < FDIM; ++f) {
#pragma unroll
        for (int m = 0; m < 5; ++m) {
            float w = Wc[(f * 5 + m) * HID + col];
            const float* xp = &xt[m * CCH + f * 16 + q * 4];
            float4 xa = *(const float4*)xp;
            acc[0] += xa.x * w; acc[1] += xa.y * w; acc[2] += xa.z * w; acc[3] += xa.w * w;
        }
    }
#pragma unroll
    for (int i = 0; i < 4; ++i) {
        int b = q * 4 + i;
        float c = tanhf(acc[i]);
        size_t idx = (size_t)b * SN + n * HID + col;
        float uv = U[idx];
        float s = state[idx];
        float ns = uv * s + (1.f - uv) * c;
        out[idx] = ns;
        out[OUTHALF + idx] = ns;
    }
}

// ---------------- launch ----------------

extern "C" void kernel_launch(void* const* d_in, const int* in_sizes, int n_in,
                              void* d_out, int out_size, void* d_ws, size_t ws_size,
                              hipStream_t stream) {
    const float* inputs = (const float*)d_in[0];
    const float* state  = (const float*)d_in[1];
    const int*   esrc   = (const int*)d_in[2];
    const int*   edst   = (const int*)d_in[3];
    const float* v1     = (const float*)d_in[4];
    const float* v2     = (const float*)d_in[5];
    const float* Wg     = (const float*)d_in[6];
    const float* bg     = (const float*)d_in[7];
    const float* Wc     = (const float*)d_in[8];
    const float* bc     = (const float*)d_in[9];
    float* out = (float*)d_out;

    char* ws = (char*)d_ws;
    size_t off = 0;
    auto alloc = [&](size_t bytes) -> void* {
        void* p = ws + off;
        off += (bytes + 255) & ~(size_t)255;
        return p;
    };
    float* X       = (float*)alloc((size_t)5 * NFB * 4);  // 173 MB: X0..X4
    float* U       = (float*)alloc((size_t)OUTHALF * 4);  // 33.5 MB
    int*   counts1 = (int*)alloc(NNODES * 4);
    int*   counts2 = (int*)alloc(NNODES * 4);
    int*   rowptr1 = (int*)alloc((NNODES + 1) * 4);
    int*   rowptr2 = (int*)alloc((NNODES + 1) * 4);
    int*   cursor1 = (int*)alloc(NNODES * 4);
    int*   cursor2 = (int*)alloc(NNODES * 4);
    int*   cols1   = (int*)alloc(NEDGE * 4);
    int*   cols2   = (int*)alloc(NEDGE * 4);
    float* valsC1  = (float*)alloc(NEDGE * 4);
    float* valsC2  = (float*)alloc(NEDGE * 4);

    float* X0 = X;
    float* X1 = X + (size_t)1 * NFB;
    float* X2 = X + (size_t)2 * NFB;
    float* X3 = X + (size_t)3 * NFB;
    float* X4 = X + (size_t)4 * NFB;

    // CSR build (graph is identical for both diff_convs)
    zero_counts_kernel<<<(NNODES + 255) / 256, 256, 0, stream>>>(counts1, counts2);
    hist_kernel<<<(NEDGE + 255) / 256, 256, 0, stream>>>(esrc, edst, counts1, counts2);
    scan_kernel<<<1, 1024, 0, stream>>>(counts1, rowptr1, cursor1);
    scan_kernel<<<1, 1024, 0, stream>>>(counts2, rowptr2, cursor2);
    scatter_kernel<<<(NEDGE + 255) / 256, 256, 0, stream>>>(esrc, edst, v1, v2,
                                                            cursor1, cursor2,
                                                            cols1, valsC1, cols2, valsC2);

    // x0 = concat(inputs, state) in [n][f][b]
    build_x0_kernel<<<(NFB + 255) / 256, 256, 0, stream>>>(inputs, state, X0);

    // diff_conv #1 diffusion
    spmm_kernel<<<NNODES, 256, 0, stream>>>(rowptr1, cols1, valsC1, X0, X0, X1, 1.f, 0.f);
    spmm_kernel<<<NNODES, 256, 0, stream>>>(rowptr1, cols1, valsC1, X1, X0, X2, 2.f, -1.f);
    spmm_kernel<<<NNODES, 256, 0, stream>>>(rowptr2, cols2, valsC2, X0, X0, X3, 1.f, 0.f);
    spmm_kernel<<<NNODES, 256, 0, stream>>>(rowptr2, cols2, valsC2, X3, X0, X4, 2.f, -1.f);

    // gate GEMM + sigmoid; writes U and overwrites X0 state-part with r*state (-> xc)
    gate_kernel<<<NNODES, 256, 0, stream>>>(X, Wg, bg, state, U, X0);

    // diff_conv #2 diffusion on xc
    spmm_kernel<<<NNODES, 256, 0, stream>>>(rowptr1, cols1, valsC1, X0, X0, X1, 1.f, 0.f);
    spmm_kernel<<<NNODES, 256, 0, stream>>>(rowptr1, cols1, valsC1, X1, X0, X2, 2.f, -1.f);
    spmm_kernel<<<NNODES, 256, 0, stream>>>(rowptr2, cols2, valsC2, X0, X0, X3, 1.f, 0.f);
    spmm_kernel<<<NNODES, 256, 0, stream>>>(rowptr2, cols2, valsC2, X3, X0, X4, 2.f, -1.f);

    // candidate GEMM + tanh + GRU update + duplicated output
    cand_kernel<<<NNODES, 256, 0, stream>>>(X, Wc, bc, state, U, out);
}

// Round 3
// 632.694 us; speedup vs baseline: 1.8659x; 1.8659x over previous
//
#include <hip/hip_runtime.h>
#include <cstddef>
#include <cstdint>

#define NNODES 8192
#define BATCH  16
#define FDIM   66      // IN_DIM + HID
#define HID    64
#define CCH    1056    // FDIM * BATCH channels per node
#define NEDGE  131072
#define NFB    8650752 // NNODES * CCH
#define SN     524288  // NNODES * HID  (per-batch state stride)
#define OUTHALF 8388608 // BATCH * SN
#define KPAD   352     // 11 * 32 (K=330 zero-padded)
#define LDA    360     // LDS A-tile row stride in bf16 elems (stride 720B -> 2-way bank alias, free)
#define GN     8       // nodes per GEMM block

typedef __attribute__((ext_vector_type(8))) short bf16x8;
typedef __attribute__((ext_vector_type(4))) float f32x4;

static __device__ __forceinline__ float bf2f(ushort u) {
    union { uint32_t i; float f; } c; c.i = ((uint32_t)u) << 16; return c.f;
}
static __device__ __forceinline__ ushort f2bf(float f) {
    union { float f; uint32_t i; } c; c.f = f;
    uint32_t lsb = (c.i >> 16) & 1;
    return (ushort)((c.i + 0x7fffu + lsb) >> 16);
}

// ---------------- CSR construction ----------------

__global__ void zero_counts_kernel(int* __restrict__ c1, int* __restrict__ c2) {
    int i = blockIdx.x * 256 + threadIdx.x;
    if (i < NNODES) { c1[i] = 0; c2[i] = 0; }
}

__global__ void hist_kernel(const int* __restrict__ src, const int* __restrict__ dst,
                            int* __restrict__ c1, int* __restrict__ c2) {
    int e = blockIdx.x * 256 + threadIdx.x;
    if (e < NEDGE) {
        atomicAdd(&c1[src[e]], 1);
        atomicAdd(&c2[dst[e]], 1);
    }
}

__global__ __launch_bounds__(1024) void scan_kernel(const int* __restrict__ counts,
                                                    int* __restrict__ rowptr,
                                                    int* __restrict__ cursor) {
    __shared__ int sh[1024];
    int tid = threadIdx.x;
    int base = tid * 8;
    int local[8];
    int sum = 0;
#pragma unroll
    for (int j = 0; j < 8; ++j) { local[j] = counts[base + j]; sum += local[j]; }
    sh[tid] = sum;
    __syncthreads();
    for (int off = 1; off < 1024; off <<= 1) {
        int v = (tid >= off) ? sh[tid - off] : 0;
        __syncthreads();
        sh[tid] += v;
        __syncthreads();
    }
    int p = sh[tid] - sum;
#pragma unroll
    for (int j = 0; j < 8; ++j) {
        cursor[base + j] = p;
        p += local[j];
        rowptr[base + j + 1] = p;
    }
    if (tid == 0) rowptr[0] = 0;
}

__global__ void scatter_kernel(const int* __restrict__ src, const int* __restrict__ dst,
                               const float* __restrict__ v1, const float* __restrict__ v2,
                               int* __restrict__ cur1, int* __restrict__ cur2,
                               int* __restrict__ cols1, float* __restrict__ valsC1,
                               int* __restrict__ cols2, float* __restrict__ valsC2) {
    int e = blockIdx.x * 256 + threadIdx.x;
    if (e < NEDGE) {
        int r1 = src[e];
        int p1 = atomicAdd(&cur1[r1], 1);
        cols1[p1] = dst[e];
        valsC1[p1] = v1[e];
        int r2 = dst[e];
        int p2 = atomicAdd(&cur2[r2], 1);
        cols2[p2] = src[e];
        valsC2[p2] = v2[e];
    }
}

// ---------------- weight transpose + bf16 convert: W[K][C] -> WT[C][KPAD] ----------------

__global__ void convert_w_kernel(const float* __restrict__ Wg, const float* __restrict__ Wc,
                                 ushort* __restrict__ WgT, ushort* __restrict__ WcT) {
    int i = blockIdx.x * 256 + threadIdx.x;
    if (i >= 192 * KPAD) return;
    int col = i / KPAD, kk = i - col * KPAD;
    if (col < 128) {
        WgT[col * KPAD + kk] = (kk < 330) ? f2bf(Wg[kk * 128 + col]) : (ushort)0;
    } else {
        int c = col - 128;
        WcT[c * KPAD + kk] = (kk < 330) ? f2bf(Wc[kk * 64 + c]) : (ushort)0;
    }
}

// ---------------- build x0 (bf16): X0[n][f][b] ----------------

__global__ void build_x0_kernel(const float* __restrict__ inputs, const float* __restrict__ state,
                                ushort* __restrict__ X0) {
    int idx = blockIdx.x * 256 + threadIdx.x;
    if (idx >= NFB) return;
    int b = idx & 15;
    int t = idx >> 4;
    int f = t % FDIM;
    int n = t / FDIM;
    float v;
    if (f < 2) v = inputs[(size_t)b * (NNODES * 2) + n * 2 + f];
    else       v = state[(size_t)b * SN + n * HID + (f - 2)];
    X0[idx] = f2bf(v);
}

// ---------------- SPMM (bf16 rows, fp32 accumulate) ----------------

static __device__ __forceinline__ void fma8(float* acc, uint4 d, float v) {
    acc[0] += v * bf2f((ushort)(d.x));  acc[1] += v * bf2f((ushort)(d.x >> 16));
    acc[2] += v * bf2f((ushort)(d.y));  acc[3] += v * bf2f((ushort)(d.y >> 16));
    acc[4] += v * bf2f((ushort)(d.z));  acc[5] += v * bf2f((ushort)(d.z >> 16));
    acc[6] += v * bf2f((ushort)(d.w));  acc[7] += v * bf2f((ushort)(d.w >> 16));
}

static __device__ __forceinline__ uint4 blend_pack8(const float* acc, uint4 p,
                                                    float alpha, float beta) {
    float o[8];
    o[0] = alpha * acc[0] + beta * bf2f((ushort)(p.x));
    o[1] = alpha * acc[1] + beta * bf2f((ushort)(p.x >> 16));
    o[2] = alpha * acc[2] + beta * bf2f((ushort)(p.y));
    o[3] = alpha * acc[3] + beta * bf2f((ushort)(p.y >> 16));
    o[4] = alpha * acc[4] + beta * bf2f((ushort)(p.z));
    o[5] = alpha * acc[5] + beta * bf2f((ushort)(p.z >> 16));
    o[6] = alpha * acc[6] + beta * bf2f((ushort)(p.w));
    o[7] = alpha * acc[7] + beta * bf2f((ushort)(p.w >> 16));
    uint4 r;
    r.x = (uint32_t)f2bf(o[0]) | ((uint32_t)f2bf(o[1]) << 16);
    r.y = (uint32_t)f2bf(o[2]) | ((uint32_t)f2bf(o[3]) << 16);
    r.z = (uint32_t)f2bf(o[4]) | ((uint32_t)f2bf(o[5]) << 16);
    r.w = (uint32_t)f2bf(o[6]) | ((uint32_t)f2bf(o[7]) << 16);
    return r;
}

__global__ __launch_bounds__(128) void spmm_kernel(const int* __restrict__ rowptr,
                                                   const int* __restrict__ cols,
                                                   const float* __restrict__ vals,
                                                   const ushort* __restrict__ x,
                                                   const ushort* __restrict__ xp,
                                                   ushort* __restrict__ y,
                                                   float alpha, float beta) {
    int n = blockIdx.x;
    int t = threadIdx.x;
    int s = rowptr[n], e = rowptr[n + 1];
    float a0[8] = {0, 0, 0, 0, 0, 0, 0, 0};
    float a1[8] = {0, 0, 0, 0, 0, 0, 0, 0};
    bool tail = t < 4;  // 132 chunks of 8 bf16
    for (int i = s; i < e; ++i) {
        float v = vals[i];
        int c = cols[i];
        const uint4* xb = (const uint4*)(x + (size_t)c * CCH);
        fma8(a0, xb[t], v);
        if (tail) fma8(a1, xb[128 + t], v);
    }
    uint4* yb = (uint4*)(y + (size_t)n * CCH);
    const uint4* xpb = (const uint4*)(xp + (size_t)n * CCH);
    uint4 p0 = (beta != 0.f) ? xpb[t] : make_uint4(0, 0, 0, 0);
    yb[t] = blend_pack8(a0, p0, alpha, beta);
    if (tail) {
        uint4 p1 = (beta != 0.f) ? xpb[128 + t] : make_uint4(0, 0, 0, 0);
        yb[128 + t] = blend_pack8(a1, p1, alpha, beta);
    }
}

// ---------------- gate GEMM (MFMA) + sigmoid + r*state writeback + u store ----------------

__global__ __launch_bounds__(256) void gate_mfma(const ushort* __restrict__ Xb,
                                                 const ushort* __restrict__ WgT,
                                                 const float* __restrict__ bg,
                                                 const float* __restrict__ state,
                                                 float* __restrict__ U,
                                                 ushort* __restrict__ X0mut) {
    __shared__ __align__(16) ushort At[16 * LDA];
    int tid = threadIdx.x;
    int wave = tid >> 6, lane = tid & 63;
    int row = lane & 15, quad = lane >> 4;
    int c0 = (wave * 2) * 16 + row;
    int c1 = (wave * 2 + 1) * 16 + row;

    bf16x8 w0[11], w1[11];
#pragma unroll
    for (int k = 0; k < 11; ++k) {
        w0[k] = *(const bf16x8*)(WgT + (size_t)c0 * KPAD + k * 32 + quad * 8);
        w1[k] = *(const bf16x8*)(WgT + (size_t)c1 * KPAD + k * 32 + quad * 8);
    }
    float bias0 = bg[c0], bias1 = bg[c1];

    // zero K-pad region (kk 330..351 for ALL 16 rows): 16*22 = 352 entries, 256 threads
    for (int p = tid; p < 16 * 22; p += 256) {
        int b = p / 22, kk = 330 + p % 22;
        At[b * LDA + kk] = 0;
    }

    int nodeBase = blockIdx.x * GN;
    for (int g = 0; g < GN; ++g) {
        int n = nodeBase + g;
        __syncthreads();
        // stage node n: 2640 ushort2 pairs, [m][f][b] -> At[b][f*5+m]
        for (int p = tid; p < 2640; p += 256) {
            int m = p / 528;
            int r2 = p - m * 528;
            int f = r2 >> 3;
            int bp = r2 & 7;
            uint d = *(const uint*)(Xb + (size_t)m * NFB + (size_t)n * CCH + f * 16 + bp * 2);
            int kk = f * 5 + m;
            int b = bp * 2;
            At[b * LDA + kk] = (ushort)d;
            At[(b + 1) * LDA + kk] = (ushort)(d >> 16);
        }
        __syncthreads();

        f32x4 acc0 = {0.f, 0.f, 0.f, 0.f};
        f32x4 acc1 = {0.f, 0.f, 0.f, 0.f};
#pragma unroll
        for (int k = 0; k < 11; ++k) {
            bf16x8 av = *(const bf16x8*)(At + row * LDA + k * 32 + quad * 8);
            acc0 = __builtin_amdgcn_mfma_f32_16x16x32_bf16(av, w0[k], acc0, 0, 0, 0);
            acc1 = __builtin_amdgcn_mfma_f32_16x16x32_bf16(av, w1[k], acc1, 0, 0, 0);
        }
        // D: col = lane&15 (-> c0/c1), row b = quad*4 + reg
#pragma unroll
        for (int r = 0; r < 4; ++r) {
            int b = quad * 4 + r;
            float v0 = 1.f / (1.f + __expf(-(acc0[r] + bias0)));
            float v1 = 1.f / (1.f + __expf(-(acc1[r] + bias1)));
            if (wave < 2) {  // cols 0..63: r-gate -> xc state part (bf16, in place)
                float s0 = state[(size_t)b * SN + n * HID + c0];
                float s1 = state[(size_t)b * SN + n * HID + c1];
                X0mut[(size_t)n * CCH + (2 + c0) * 16 + b] = f2bf(v0 * s0);
                X0mut[(size_t)n * CCH + (2 + c1) * 16 + b] = f2bf(v1 * s1);
            } else {         // cols 64..127: u-gate (fp32)
                U[(size_t)b * SN + n * HID + (c0 - HID)] = v0;
                U[(size_t)b * SN + n * HID + (c1 - HID)] = v1;
            }
        }
    }
}

// ---------------- candidate GEMM (MFMA) + tanh + GRU update + output ----------------

__global__ __launch_bounds__(256) void cand_mfma(const ushort* __restrict__ Xb,
                                                 const ushort* __restrict__ WcT,
                                                 const float* __restrict__ bc,
                                                 const float* __restrict__ state,
                                                 const float* __restrict__ U,
                                                 float* __restrict__ out) {
    __shared__ __align__(16) ushort At[16 * LDA];
    int tid = threadIdx.x;
    int wave = tid >> 6, lane = tid & 63;
    int row = lane & 15, quad = lane >> 4;
    int c = wave * 16 + row;

    bf16x8 w[11];
#pragma unroll
    for (int k = 0; k < 11; ++k)
        w[k] = *(const bf16x8*)(WcT + (size_t)c * KPAD + k * 32 + quad * 8);
    float bias = bc[c];

    for (int p = tid; p < 16 * 22; p += 256) {
        int b = p / 22, kk = 330 + p % 22;
        At[b * LDA + kk] = 0;
    }

    int nodeBase = blockIdx.x * GN;
    for (int g = 0; g < GN; ++g) {
        int n = nodeBase + g;
        __syncthreads();
        for (int p = tid; p < 2640; p += 256) {
            int m = p / 528;
            int r2 = p - m * 528;
            int f = r2 >> 3;
            int bp = r2 & 7;
            uint d = *(const uint*)(Xb + (size_t)m * NFB + (size_t)n * CCH + f * 16 + bp * 2);
            int kk = f * 5 + m;
            int b = bp * 2;
            At[b * LDA + kk] = (ushort)d;
            At[(b + 1) * LDA + kk] = (ushort)(d >> 16);
        }
        __syncthreads();

        f32x4 acc = {0.f, 0.f, 0.f, 0.f};
#pragma unroll
        for (int k = 0; k < 11; ++k) {
            bf16x8 av = *(const bf16x8*)(At + row * LDA + k * 32 + quad * 8);
            acc = __builtin_amdgcn_mfma_f32_16x16x32_bf16(av, w[k], acc, 0, 0, 0);
        }
#pragma unroll
        for (int r = 0; r < 4; ++r) {
            int b = quad * 4 + r;
            float pre = acc[r] + bias;
            // tanh(x) = 1 - 2/(exp(2x)+1)
            float cv = 1.f - 2.f / (__expf(2.f * pre) + 1.f);
            size_t idx = (size_t)b * SN + n * HID + c;
            float uv = U[idx];
            float s = state[idx];
            float ns = uv * s + (1.f - uv) * cv;
            out[idx] = ns;
            out[OUTHALF + idx] = ns;
        }
    }
}

// ---------------- launch ----------------

extern "C" void kernel_launch(void* const* d_in, const int* in_sizes, int n_in,
                              void* d_out, int out_size, void* d_ws, size_t ws_size,
                              hipStream_t stream) {
    const float* inputs = (const float*)d_in[0];
    const float* state  = (const float*)d_in[1];
    const int*   esrc   = (const int*)d_in[2];
    const int*   edst   = (const int*)d_in[3];
    const float* v1     = (const float*)d_in[4];
    const float* v2     = (const float*)d_in[5];
    const float* Wg     = (const float*)d_in[6];
    const float* bg     = (const float*)d_in[7];
    const float* Wc     = (const float*)d_in[8];
    const float* bc     = (const float*)d_in[9];
    float* out = (float*)d_out;

    char* ws = (char*)d_ws;
    size_t off = 0;
    auto alloc = [&](size_t bytes) -> void* {
        void* p = ws + off;
        off += (bytes + 255) & ~(size_t)255;
        return p;
    };
    ushort* Xb     = (ushort*)alloc((size_t)5 * NFB * 2);  // 86.5 MB bf16 X0..X4
    float*  U      = (float*)alloc((size_t)OUTHALF * 4);   // 33.5 MB
    ushort* WgT    = (ushort*)alloc((size_t)128 * KPAD * 2);
    ushort* WcT    = (ushort*)alloc((size_t)64 * KPAD * 2);
    int*   counts1 = (int*)alloc(NNODES * 4);
    int*   counts2 = (int*)alloc(NNODES * 4);
    int*   rowptr1 = (int*)alloc((NNODES + 1) * 4);
    int*   rowptr2 = (int*)alloc((NNODES + 1) * 4);
    int*   cursor1 = (int*)alloc(NNODES * 4);
    int*   cursor2 = (int*)alloc(NNODES * 4);
    int*   cols1   = (int*)alloc(NEDGE * 4);
    int*   cols2   = (int*)alloc(NEDGE * 4);
    float* valsC1  = (float*)alloc(NEDGE * 4);
    float* valsC2  = (float*)alloc(NEDGE * 4);

    ushort* X0 = Xb;
    ushort* X1 = Xb + (size_t)1 * NFB;
    ushort* X2 = Xb + (size_t)2 * NFB;
    ushort* X3 = Xb + (size_t)3 * NFB;
    ushort* X4 = Xb + (size_t)4 * NFB;

    // CSR build (graph shared by both diff_convs)
    zero_counts_kernel<<<(NNODES + 255) / 256, 256, 0, stream>>>(counts1, counts2);
    hist_kernel<<<(NEDGE + 255) / 256, 256, 0, stream>>>(esrc, edst, counts1, counts2);
    scan_kernel<<<1, 1024, 0, stream>>>(counts1, rowptr1, cursor1);
    scan_kernel<<<1, 1024, 0, stream>>>(counts2, rowptr2, cursor2);
    scatter_kernel<<<(NEDGE + 255) / 256, 256, 0, stream>>>(esrc, edst, v1, v2,
                                                            cursor1, cursor2,
                                                            cols1, valsC1, cols2, valsC2);

    convert_w_kernel<<<(192 * KPAD + 255) / 256, 256, 0, stream>>>(Wg, Wc, WgT, WcT);
    build_x0_kernel<<<(NFB + 255) / 256, 256, 0, stream>>>(inputs, state, X0);

    // diff_conv #1 diffusion
    spmm_kernel<<<NNODES, 128, 0, stream>>>(rowptr1, cols1, valsC1, X0, X0, X1, 1.f, 0.f);
    spmm_kernel<<<NNODES, 128, 0, stream>>>(rowptr1, cols1, valsC1, X1, X0, X2, 2.f, -1.f);
    spmm_kernel<<<NNODES, 128, 0, stream>>>(rowptr2, cols2, valsC2, X0, X0, X3, 1.f, 0.f);
    spmm_kernel<<<NNODES, 128, 0, stream>>>(rowptr2, cols2, valsC2, X3, X0, X4, 2.f, -1.f);

    // gate GEMM + sigmoid; writes U, overwrites X0 state-part with r*state (-> xc)
    gate_mfma<<<NNODES / GN, 256, 0, stream>>>(Xb, WgT, bg, state, U, X0);

    // diff_conv #2 diffusion on xc
    spmm_kernel<<<NNODES, 128, 0, stream>>>(rowptr1, cols1, valsC1, X0, X0, X1, 1.f, 0.f);
    spmm_kernel<<<NNODES, 128, 0, stream>>>(rowptr1, cols1, valsC1, X1, X0, X2, 2.f, -1.f);
    spmm_kernel<<<NNODES, 128, 0, stream>>>(rowptr2, cols2, valsC2, X0, X0, X3, 1.f, 0.f);
    spmm_kernel<<<NNODES, 128, 0, stream>>>(rowptr2, cols2, valsC2, X3, X0, X4, 2.f, -1.f);

    // candidate GEMM + tanh + GRU update + duplicated output
    cand_mfma<<<NNODES / GN, 256, 0, stream>>>(Xb, WcT, bc, state, U, out);
}